// Round 6
// baseline (375.938 us; speedup 1.0000x reference)
//
#include <hip/hip_runtime.h>
#include <cstdint>
#include <math.h>

#define TT 2048
#define CC 1024
#define HH 16
#define DH 64
#define BB 4
#define MM 8192   // B*T

typedef unsigned short u16;
typedef __bf16 bf16_t;
typedef bf16_t bf16x8 __attribute__((ext_vector_type(8)));
typedef float f32x4 __attribute__((ext_vector_type(4)));

// fp32 -> bf16 round-to-nearest-even (scalar)
static __device__ inline u16 f2bf(float f) {
    unsigned int u = __builtin_bit_cast(unsigned int, f);
    unsigned int lsb = (u >> 16) & 1u;
    u += 0x7fffu + lsb;
    return (u16)(u >> 16);
}

// packed 2xfp32 -> 2xbf16 (gfx950 v_cvt_pk_bf16_f32, RNE) — 1 op per 2 values
static __device__ inline unsigned int cvt_pk_bf16(float a, float b) {
    unsigned int r;
    asm volatile("v_cvt_pk_bf16_f32 %0, %1, %2" : "=v"(r) : "v"(a), "v"(b));
    return r;
}

// async 16B global->LDS (m97 pattern: LDS dest lane-linear 16B)
#define GLL16(gptr, lptr)                                                            \
    __builtin_amdgcn_global_load_lds(                                                \
        (__attribute__((address_space(1))) void*)(gptr),                             \
        (__attribute__((address_space(3))) void*)(lptr), 16, 0, 0)

// ---------------- prep kernels ----------------

__global__ void cast_x_kernel(const float* __restrict__ x, u16* __restrict__ xb, int n4) {
    int i = blockIdx.x * blockDim.x + threadIdx.x;
    if (i >= n4) return;
    float4 v = ((const float4*)x)[i];
    uint2 o;
    o.x = cvt_pk_bf16(v.x, v.y);
    o.y = cvt_pk_bf16(v.z, v.w);
    ((uint2*)xb)[i] = o;
}

// Tiled W[K][N] fp32 -> Wt[N][K] bf16 (coalesced both sides via LDS 32x32 tile).
__global__ void __launch_bounds__(256)
transpose_cast_kernel(const float* __restrict__ W, u16* __restrict__ Wt, int K, int N) {
    __shared__ u16 tile[32 * 34];   // [n][k], pad 34 u16 = 17 words (odd: conflict-free)
    const int tx = threadIdx.x & 31;
    const int ty = threadIdx.x >> 5;       // 0..7
    const int n0 = blockIdx.x * 32;
    const int k0 = blockIdx.y * 32;
#pragma unroll
    for (int i = 0; i < 4; ++i) {
        int k = ty + i * 8;                // 0..31
        tile[tx * 34 + k] = f2bf(W[(size_t)(k0 + k) * N + n0 + tx]);
    }
    __syncthreads();
    const int tx2 = threadIdx.x & 15;      // uint column: k = 2*tx2 (0..30)
    const int ty2 = threadIdx.x >> 4;      // 0..15
#pragma unroll
    for (int i = 0; i < 2; ++i) {
        int r = ty2 + i * 16;              // n-row 0..31
        *(unsigned int*)&Wt[(size_t)(n0 + r) * K + k0 + 2 * tx2] =
            *(unsigned int*)&tile[r * 34 + 2 * tx2];
    }
}

// ---------------- GEMM: C[M,N] = A[M,K] @ Bt[N,K]^T + bias ----------------
// ROUND-8 STRUCTURE (verified fastest): 128x128 tile, 4 waves (2x2), BK=32,
// GLL16 staging of A and B into DOUBLE-BUFFERED LDS, ONE barrier per k-step.
// MODE 0: A is y in [B,H,T,Dh] bf16; write fp32 C.
// MODE 1: A row-major [M,K] bf16; qkv scatter epilogue. V^T is stored with a
//   per-64-key-tile chunk permutation (4-key chunks [s3s2s1s0]->[s3,s1,s0,s2])
//   so the attention PV B-operand can be fed DIRECTLY from the QK output
//   registers (see attn_kernel round-13 notes).
template <int MODE>
__global__ void __launch_bounds__(256)
gemm_bt_kernel(const u16* __restrict__ A, const u16* __restrict__ Bt,
               const float* __restrict__ bias, float* __restrict__ Cout,
               u16* __restrict__ qws, u16* __restrict__ kws, u16* __restrict__ vtws,
               int Mdim, int Ndim, int Kdim) {
    __shared__ u16 As[2][128 * 32];
    __shared__ u16 Bs[2][128 * 32];

    const int tid  = threadIdx.x;
    const int w    = tid >> 6;
    const int lane = tid & 63;
    const int l15  = lane & 15;
    const int quad = lane >> 4;
    const int wm   = (w & 1) * 64;
    const int wn   = (w >> 1) * 64;
    const int m0   = blockIdx.y * 128;
    const int n0   = blockIdx.x * 128;

    const int row0  = tid >> 2;              // 0..63
    const int row1  = row0 + 64;             // 64..127
    const int col8  = (tid & 3) << 3;        // 0,8,16,24

    f32x4 acc[4][4];
#pragma unroll
    for (int i = 0; i < 4; ++i)
#pragma unroll
        for (int j = 0; j < 4; ++j) acc[i][j] = (f32x4){0.f, 0.f, 0.f, 0.f};

    auto stageA = [&](int buf, int kc) {
        if (MODE == 0) {
            int kcc = kc + col8, h = kcc >> 6, d = kcc & 63;
            int m = m0 + row0, b = m >> 11, t = m & 2047;
            GLL16(&A[(((size_t)(b * HH + h) * TT + t) * DH) + d], &As[buf][tid * 8]);
            m = m0 + row1; b = m >> 11; t = m & 2047;
            GLL16(&A[(((size_t)(b * HH + h) * TT + t) * DH) + d], &As[buf][(tid + 256) * 8]);
        } else {
            GLL16(&A[(size_t)(m0 + row0) * Kdim + kc + col8], &As[buf][tid * 8]);
            GLL16(&A[(size_t)(m0 + row1) * Kdim + kc + col8], &As[buf][(tid + 256) * 8]);
        }
    };

    // prologue: stage tile 0 into buffer 0
    stageA(0, 0);
    GLL16(&Bt[(size_t)(n0 + row0) * Kdim + col8], &Bs[0][tid * 8]);
    GLL16(&Bt[(size_t)(n0 + row1) * Kdim + col8], &Bs[0][(tid + 256) * 8]);

    const int nsteps = Kdim >> 5;
    for (int it = 0; it < nsteps; ++it) {
        const int buf = it & 1;
        __syncthreads();   // publishes tile `it` (drains its GLL16s — issued a full step ago)

        if (it + 1 < nsteps) {
            const int nbuf = buf ^ 1;
            const int kc = (it + 1) << 5;
            stageA(nbuf, kc);
            GLL16(&Bt[(size_t)(n0 + row0) * Kdim + kc + col8], &Bs[nbuf][tid * 8]);
            GLL16(&Bt[(size_t)(n0 + row1) * Kdim + kc + col8], &Bs[nbuf][(tid + 256) * 8]);
        }

        bf16x8 af[4], bfm[4];
#pragma unroll
        for (int mt = 0; mt < 4; ++mt)
            af[mt] = *(const bf16x8*)&As[buf][(wm + mt * 16 + l15) * 32 + quad * 8];
#pragma unroll
        for (int nt = 0; nt < 4; ++nt)
            bfm[nt] = *(const bf16x8*)&Bs[buf][(wn + nt * 16 + l15) * 32 + quad * 8];
#pragma unroll
        for (int mt = 0; mt < 4; ++mt)
#pragma unroll
            for (int nt = 0; nt < 4; ++nt)
                acc[mt][nt] = __builtin_amdgcn_mfma_f32_16x16x32_bf16(
                    af[mt], bfm[nt], acc[mt][nt], 0, 0, 0);
    }

    // epilogue: D row = quad*4+r, col = l15
#pragma unroll
    for (int mt = 0; mt < 4; ++mt) {
        int mrow_base = m0 + wm + mt * 16 + quad * 4;
#pragma unroll
        for (int nt = 0; nt < 4; ++nt) {
            int ncol = n0 + wn + nt * 16 + l15;
            float bv = bias[ncol];
            if (MODE == 0) {
#pragma unroll
                for (int r = 0; r < 4; ++r)
                    Cout[(size_t)(mrow_base + r) * Ndim + ncol] = acc[mt][nt][r] + bv;
            } else {
                int which = ncol >> 10, c = ncol & 1023;
                int h = c >> 6, d = c & 63;
                if (which == 2) {
                    // V^T: r spans 4 consecutive t -> packed store, with the
                    // key-permutation folded in: 4-key chunk [s3s2s1s0] -> [s3,s1,s0,s2]
                    int b = mrow_base >> 11, t = mrow_base & 2047;
                    int bh = b * HH + h;
                    int ch = (t >> 2) & 15;
                    int chp = (ch & 8) | (((ch >> 1) & 1) << 2) | ((ch & 1) << 1) | ((ch >> 2) & 1);
                    int tp = (t & ~63) | (chp << 2);
                    uint2 pv;
                    pv.x = cvt_pk_bf16(acc[mt][nt][0] + bv, acc[mt][nt][1] + bv);
                    pv.y = cvt_pk_bf16(acc[mt][nt][2] + bv, acc[mt][nt][3] + bv);
                    *(uint2*)&vtws[((size_t)bh * DH + d) * TT + tp] = pv;
                } else {
#pragma unroll
                    for (int r = 0; r < 4; ++r) {
                        int mrow = mrow_base + r;
                        int b = mrow >> 11, t = mrow & 2047;
                        int bh = b * HH + h;
                        float val = acc[mt][nt][r] + bv;
                        if (which == 0) {
                            // fold softmax scale and log2(e) into Q: 0.125*log2e
                            qws[((size_t)bh * TT + t) * DH + d] = f2bf(val * 0.18033688f);
                        } else {
                            kws[((size_t)bh * TT + t) * DH + d] = f2bf(val);
                        }
                    }
                }
            }
        }
    }
}

// ---------------- flash attention v10: zero-LDS P path ----------------
// ROUND-13/14, counter-driven. r4: occupancy 19.5->27% but dur only -2% ->
// the serial per-tile chain is binding, and its core is the P round-trip
// through LDS (8 ds_writes + lgkmcnt(0) drain + 4 b128 reads per tile).
// ELIMINATED via key-permutation: PV contraction slot kappa=[kk,q1,q0,j2,j1,j0]
// maps to key [kk,j2,q1,q0,j1,j0]. With V^T pre-permuted by the GEMM epilogue
// (same bijection, 4-key chunk granular), the PV B-operand is EXACTLY the
// lane's own QK output packed in order: bp(kk) = pack(s[2kk], s[2kk+1]).
// Masked slots are exp2(-inf)=0 so V permutation is harmless; the all-ones
// l-sum A-operand is permutation-invariant; per-MFMA key sets (0-31/32-63)
// are preserved. (Permutation re-derived and verified in r5 while waiting
// for hardware: tp4=t3, tp3=t2, tp2=t4, tp1=t1, tp0=t0; code matches.)
//  * Ps buffer deleted -> LDS 52224 -> 34816 B -> 4 blocks/CU.
//  * No lgkmcnt drain, no P ds-ops in the chain: barrier -> K reads ->
//    QK MFMA -> mask/exp2/pack -> PV MFMA.
__global__ void __launch_bounds__(256, 4)
attn_kernel(const u16* __restrict__ qws, const u16* __restrict__ kws,
            const u16* __restrict__ vtws, u16* __restrict__ yws) {
    __shared__ u16 Ks[2][64 * 68];   // K tile  [key][d], stride 68 u16 (bank-balanced)
    __shared__ u16 Vs[2][64 * 68];   // V^T tile [d][key-permuted]

    const int tid  = threadIdx.x;
    const int w    = tid >> 6;       // 0..3
    const int lane = tid & 63;
    const int l15  = lane & 15;
    const int quad = lane >> 4;
    const int bh   = blockIdx.x;     // fast index: co-locates same-bh blocks per XCD
    const int qt   = 15 - blockIdx.y;   // heavy tiles first

    const u16* Kbase = kws + (size_t)bh * TT * DH;
    const u16* Vbase = vtws + (size_t)bh * DH * TT;

    // staging: 256 threads x 32B each for K and V (fully coalesced)
    const int srow  = tid >> 2;          // 0..63
    const int sc16  = (tid & 3) << 4;    // 0,16,32,48 (u16 units)

    bf16x8 aones;
#pragma unroll
    for (int i = 0; i < 8; ++i) aones[i] = __builtin_bit_cast(bf16_t, (u16)0x3F80);

    const int q0     = qt * 128;
    const int qr0    = q0 + w * 32;    // this wave's 32 queries
    const int ntiles = (q0 + 128) >> 6;

    // Q fragments as B-operand (lane=query, contiguous d); scale+log2e folded
    const u16* Qp = qws + ((size_t)bh * TT + qr0) * DH;
    bf16x8 bqa[2], bqb[2];
#pragma unroll
    for (int kk = 0; kk < 2; ++kk) {
        bqa[kk] = *(const bf16x8*)&Qp[l15 * DH + kk * 32 + quad * 8];
        bqb[kk] = *(const bf16x8*)&Qp[(16 + l15) * DH + kk * 32 + quad * 8];
    }

    f32x4 o[2][4], ol[2];
#pragma unroll
    for (int qg = 0; qg < 2; ++qg) {
#pragma unroll
        for (int dt = 0; dt < 4; ++dt) o[qg][dt] = (f32x4){0.f, 0.f, 0.f, 0.f};
        ol[qg] = (f32x4){0.f, 0.f, 0.f, 0.f};
    }

    // prologue: tile 0 -> regs -> LDS[0]; tile 1 -> regs
    uint4 pk0 = *(const uint4*)&Kbase[(size_t)srow * DH + sc16];
    uint4 pk1 = *(const uint4*)&Kbase[(size_t)srow * DH + sc16 + 8];
    uint4 pv0 = *(const uint4*)&Vbase[(size_t)srow * TT + sc16];
    uint4 pv1 = *(const uint4*)&Vbase[(size_t)srow * TT + sc16 + 8];
    *(uint4*)&Ks[0][srow * 68 + sc16]     = pk0;
    *(uint4*)&Ks[0][srow * 68 + sc16 + 8] = pk1;
    *(uint4*)&Vs[0][srow * 68 + sc16]     = pv0;
    *(uint4*)&Vs[0][srow * 68 + sc16 + 8] = pv1;
    if (ntiles > 1) {
        pk0 = *(const uint4*)&Kbase[(size_t)(64 + srow) * DH + sc16];
        pk1 = *(const uint4*)&Kbase[(size_t)(64 + srow) * DH + sc16 + 8];
        pv0 = *(const uint4*)&Vbase[(size_t)srow * TT + 64 + sc16];
        pv1 = *(const uint4*)&Vbase[(size_t)srow * TT + 64 + sc16 + 8];
    }

    for (int it = 0; it < ntiles; ++it) {
        const int buf = it & 1;
        __syncthreads();   // publishes tile `it`; frees buffer buf^1

        if (it + 1 < ntiles) {
            *(uint4*)&Ks[buf ^ 1][srow * 68 + sc16]     = pk0;
            *(uint4*)&Ks[buf ^ 1][srow * 68 + sc16 + 8] = pk1;
            *(uint4*)&Vs[buf ^ 1][srow * 68 + sc16]     = pv0;
            *(uint4*)&Vs[buf ^ 1][srow * 68 + sc16 + 8] = pv1;
            if (it + 2 < ntiles) {
                int jn = (it + 2) << 6;
                pk0 = *(const uint4*)&Kbase[(size_t)(jn + srow) * DH + sc16];
                pk1 = *(const uint4*)&Kbase[(size_t)(jn + srow) * DH + sc16 + 8];
                pv0 = *(const uint4*)&Vbase[(size_t)srow * TT + jn + sc16];
                pv1 = *(const uint4*)&Vbase[(size_t)srow * TT + jn + sc16 + 8];
            }
        }

        const int j0 = it << 6;
        if (j0 > qr0 + 31) continue;   // fully masked for this wave (both q-groups)

        // ---- K fragments ONCE, reused by both q-groups ----
        bf16x8 ak[8];
#pragma unroll
        for (int kk = 0; kk < 2; ++kk)
#pragma unroll
            for (int kt = 0; kt < 4; ++kt)
                ak[kk * 4 + kt] =
                    *(const bf16x8*)&Ks[buf][(kt * 16 + l15) * 68 + kk * 32 + quad * 8];

        // ---- V fragments (natural b128 reads; permutation lives in vtws) ----
        bf16x8 avr[8];
#pragma unroll
        for (int kk = 0; kk < 2; ++kk)
#pragma unroll
            for (int dt = 0; dt < 4; ++dt)
                avr[kk * 4 + dt] =
                    *(const bf16x8*)&Vs[buf][(dt * 16 + l15) * 68 + kk * 32 + quad * 8];

        // ---- S^T = K @ Q^T for both q-groups ----
        f32x4 sa[4], sb[4];
#pragma unroll
        for (int kt = 0; kt < 4; ++kt) {
            sa[kt] = (f32x4){0.f, 0.f, 0.f, 0.f};
            sb[kt] = (f32x4){0.f, 0.f, 0.f, 0.f};
        }
#pragma unroll
        for (int kk = 0; kk < 2; ++kk)
#pragma unroll
            for (int kt = 0; kt < 4; ++kt)
                sa[kt] = __builtin_amdgcn_mfma_f32_16x16x32_bf16(ak[kk * 4 + kt], bqa[kk], sa[kt], 0, 0, 0);
#pragma unroll
        for (int kk = 0; kk < 2; ++kk)
#pragma unroll
            for (int kt = 0; kt < 4; ++kt)
                sb[kt] = __builtin_amdgcn_mfma_f32_16x16x32_bf16(ak[kk * 4 + kt], bqb[kk], sb[kt], 0, 0, 0);

        // causal mask (diagonal region only): key > query -> -inf
        if (j0 + 63 > qr0) {
            int qy0 = qr0 + l15;
            int qy1 = qr0 + 16 + l15;
#pragma unroll
            for (int kt = 0; kt < 4; ++kt)
#pragma unroll
                for (int r = 0; r < 4; ++r) {
                    int key = j0 + kt * 16 + quad * 4 + r;
                    if (key > qy0) sa[kt][r] = -INFINITY;
                    if (key > qy1) sb[kt][r] = -INFINITY;
                }
        }

        // ---- max-free softmax: p = exp2(s) ----
#pragma unroll
        for (int kt = 0; kt < 4; ++kt)
#pragma unroll
            for (int r = 0; r < 4; ++r) {
                sa[kt][r] = __builtin_amdgcn_exp2f(sa[kt][r]);
                sb[kt][r] = __builtin_amdgcn_exp2f(sb[kt][r]);
            }

        // ---- P -> PV B-operand DIRECTLY in-register: bp(kk) = pack(s[2kk],s[2kk+1]).
        // Slot->key bijection is matched by the permuted V^T layout. No LDS. ----
        uint4 ua0, ua1, ub0, ub1;
        ua0.x = cvt_pk_bf16(sa[0][0], sa[0][1]);
        ua0.y = cvt_pk_bf16(sa[0][2], sa[0][3]);
        ua0.z = cvt_pk_bf16(sa[1][0], sa[1][1]);
        ua0.w = cvt_pk_bf16(sa[1][2], sa[1][3]);
        ua1.x = cvt_pk_bf16(sa[2][0], sa[2][1]);
        ua1.y = cvt_pk_bf16(sa[2][2], sa[2][3]);
        ua1.z = cvt_pk_bf16(sa[3][0], sa[3][1]);
        ua1.w = cvt_pk_bf16(sa[3][2], sa[3][3]);
        ub0.x = cvt_pk_bf16(sb[0][0], sb[0][1]);
        ub0.y = cvt_pk_bf16(sb[0][2], sb[0][3]);
        ub0.z = cvt_pk_bf16(sb[1][0], sb[1][1]);
        ub0.w = cvt_pk_bf16(sb[1][2], sb[1][3]);
        ub1.x = cvt_pk_bf16(sb[2][0], sb[2][1]);
        ub1.y = cvt_pk_bf16(sb[2][2], sb[2][3]);
        ub1.z = cvt_pk_bf16(sb[3][0], sb[3][1]);
        ub1.w = cvt_pk_bf16(sb[3][2], sb[3][3]);
        bf16x8 bpa0 = __builtin_bit_cast(bf16x8, ua0);
        bf16x8 bpa1 = __builtin_bit_cast(bf16x8, ua1);
        bf16x8 bpb0 = __builtin_bit_cast(bf16x8, ub0);
        bf16x8 bpb1 = __builtin_bit_cast(bf16x8, ub1);

        // ---- O^T += V^T @ P^T ; l += ones @ P^T (fused row-sum) ----
#pragma unroll
        for (int dt = 0; dt < 4; ++dt)
            o[0][dt] = __builtin_amdgcn_mfma_f32_16x16x32_bf16(avr[dt], bpa0, o[0][dt], 0, 0, 0);
        ol[0] = __builtin_amdgcn_mfma_f32_16x16x32_bf16(aones, bpa0, ol[0], 0, 0, 0);
#pragma unroll
        for (int dt = 0; dt < 4; ++dt)
            o[0][dt] = __builtin_amdgcn_mfma_f32_16x16x32_bf16(avr[4 + dt], bpa1, o[0][dt], 0, 0, 0);
        ol[0] = __builtin_amdgcn_mfma_f32_16x16x32_bf16(aones, bpa1, ol[0], 0, 0, 0);
#pragma unroll
        for (int dt = 0; dt < 4; ++dt)
            o[1][dt] = __builtin_amdgcn_mfma_f32_16x16x32_bf16(avr[dt], bpb0, o[1][dt], 0, 0, 0);
        ol[1] = __builtin_amdgcn_mfma_f32_16x16x32_bf16(aones, bpb0, ol[1], 0, 0, 0);
#pragma unroll
        for (int dt = 0; dt < 4; ++dt)
            o[1][dt] = __builtin_amdgcn_mfma_f32_16x16x32_bf16(avr[4 + dt], bpb1, o[1][dt], 0, 0, 0);
        ol[1] = __builtin_amdgcn_mfma_f32_16x16x32_bf16(aones, bpb1, ol[1], 0, 0, 0);
    }

    // ---- normalize + store O^T to y[B,H,T,Dh] (coalesced) ----
#pragma unroll
    for (int qg = 0; qg < 2; ++qg) {
        float rinv = __builtin_amdgcn_rcpf(ol[qg][0]);   // l[query]; ~1ulp ok at bf16 out
        int t = qr0 + qg * 16 + l15;
#pragma unroll
        for (int dt = 0; dt < 4; ++dt) {
            uint2 yv;
            yv.x = cvt_pk_bf16(o[qg][dt][0] * rinv, o[qg][dt][1] * rinv);
            yv.y = cvt_pk_bf16(o[qg][dt][2] * rinv, o[qg][dt][3] * rinv);
            *(uint2*)&yws[((size_t)bh * TT + t) * DH + dt * 16 + quad * 4] = yv;
        }
    }
}

// ---------------- launch ----------------

extern "C" void kernel_launch(void* const* d_in, const int* in_sizes, int n_in,
                              void* d_out, int out_size, void* d_ws, size_t ws_size,
                              hipStream_t stream) {
    const float* x     = (const float*)d_in[0];
    const float* W_qkv = (const float*)d_in[1];
    const float* b_qkv = (const float*)d_in[2];
    const float* W_out = (const float*)d_in[3];
    const float* b_out = (const float*)d_in[4];
    float* out = (float*)d_out;

    char* ws = (char*)d_ws;
    u16* xb   = (u16*)ws; ws += (size_t)MM * CC * 2;       // x bf16        16 MB
    u16* wqt  = (u16*)ws; ws += (size_t)3 * CC * CC * 2;   // W_qkv^T bf16   6 MB
    u16* wot  = (u16*)ws; ws += (size_t)CC * CC * 2;       // W_out^T bf16   2 MB
    u16* qws  = (u16*)ws; ws += (size_t)MM * CC * 2;       // Q [B,H,T,Dh]  16 MB
    u16* kws  = (u16*)ws; ws += (size_t)MM * CC * 2;       // K [B,H,T,Dh]  16 MB
    u16* vtws = (u16*)ws; ws += (size_t)MM * CC * 2;       // V^T [B,H,Dh,T] (key-permuted) 16 MB
    u16* yws  = (u16*)ws; ws += (size_t)MM * CC * 2;       // y [B,H,T,Dh]  16 MB

    cast_x_kernel<<<(MM * CC / 4) / 256, 256, 0, stream>>>(x, xb, MM * CC / 4);
    transpose_cast_kernel<<<dim3(3 * CC / 32, CC / 32), 256, 0, stream>>>(W_qkv, wqt, CC, 3 * CC);
    transpose_cast_kernel<<<dim3(CC / 32, CC / 32), 256, 0, stream>>>(W_out, wot, CC, CC);

    gemm_bt_kernel<1><<<dim3(24, 64), 256, 0, stream>>>(
        xb, wqt, b_qkv, nullptr, qws, kws, vtws, MM, 3 * CC, CC);

    attn_kernel<<<dim3(BB * HH, 16), 256, 0, stream>>>(qws, kws, vtws, yws);

    gemm_bt_kernel<0><<<dim3(8, 64), 256, 0, stream>>>(
        yws, wot, b_out, out, nullptr, nullptr, nullptr, MM, CC, CC);
}

// Round 7
// 235.278 us; speedup vs baseline: 1.5978x; 1.5978x over previous
//
#include <hip/hip_runtime.h>
#include <cstdint>
#include <math.h>

#define TT 2048
#define CC 1024
#define HH 16
#define DH 64
#define BB 4
#define MM 8192   // B*T

typedef unsigned short u16;
typedef __bf16 bf16_t;
typedef bf16_t bf16x8 __attribute__((ext_vector_type(8)));
typedef float f32x4 __attribute__((ext_vector_type(4)));

// fp32 -> bf16 round-to-nearest-even (scalar)
static __device__ inline u16 f2bf(float f) {
    unsigned int u = __builtin_bit_cast(unsigned int, f);
    unsigned int lsb = (u >> 16) & 1u;
    u += 0x7fffu + lsb;
    return (u16)(u >> 16);
}

// packed 2xfp32 -> 2xbf16 (gfx950 v_cvt_pk_bf16_f32, RNE) — 1 op per 2 values
static __device__ inline unsigned int cvt_pk_bf16(float a, float b) {
    unsigned int r;
    asm volatile("v_cvt_pk_bf16_f32 %0, %1, %2" : "=v"(r) : "v"(a), "v"(b));
    return r;
}

// async 16B global->LDS (m97 pattern: LDS dest lane-linear 16B)
#define GLL16(gptr, lptr)                                                            \
    __builtin_amdgcn_global_load_lds(                                                \
        (__attribute__((address_space(1))) void*)(gptr),                             \
        (__attribute__((address_space(3))) void*)(lptr), 16, 0, 0)

// ---------------- prep kernels ----------------

__global__ void cast_x_kernel(const float* __restrict__ x, u16* __restrict__ xb, int n4) {
    int i = blockIdx.x * blockDim.x + threadIdx.x;
    if (i >= n4) return;
    float4 v = ((const float4*)x)[i];
    uint2 o;
    o.x = cvt_pk_bf16(v.x, v.y);
    o.y = cvt_pk_bf16(v.z, v.w);
    ((uint2*)xb)[i] = o;
}

// Tiled W[K][N] fp32 -> Wt[N][K] bf16 (coalesced both sides via LDS 32x32 tile).
__global__ void __launch_bounds__(256)
transpose_cast_kernel(const float* __restrict__ W, u16* __restrict__ Wt, int K, int N) {
    __shared__ u16 tile[32 * 34];   // [n][k], pad 34 u16 = 17 words (odd: conflict-free)
    const int tx = threadIdx.x & 31;
    const int ty = threadIdx.x >> 5;       // 0..7
    const int n0 = blockIdx.x * 32;
    const int k0 = blockIdx.y * 32;
#pragma unroll
    for (int i = 0; i < 4; ++i) {
        int k = ty + i * 8;                // 0..31
        tile[tx * 34 + k] = f2bf(W[(size_t)(k0 + k) * N + n0 + tx]);
    }
    __syncthreads();
    const int tx2 = threadIdx.x & 15;      // uint column: k = 2*tx2 (0..30)
    const int ty2 = threadIdx.x >> 4;      // 0..15
#pragma unroll
    for (int i = 0; i < 2; ++i) {
        int r = ty2 + i * 16;              // n-row 0..31
        *(unsigned int*)&Wt[(size_t)(n0 + r) * K + k0 + 2 * tx2] =
            *(unsigned int*)&tile[r * 34 + 2 * tx2];
    }
}

// ---------------- GEMM: C[M,N] = A[M,K] @ Bt[N,K]^T + bias ----------------
// ROUND-8 STRUCTURE (verified fastest): 128x128 tile, 4 waves (2x2), BK=32,
// GLL16 staging of A and B into DOUBLE-BUFFERED LDS, ONE barrier per k-step.
// MODE 0: A is y in [B,H,T,Dh] bf16; write fp32 C.
// MODE 1: A row-major [M,K] bf16; qkv scatter epilogue. V^T is stored with a
//   per-64-key-tile chunk permutation (4-key chunks [s3s2s1s0]->[s3,s1,s0,s2])
//   so the attention PV B-operand can be fed DIRECTLY from the QK output
//   registers (see attn_kernel notes).
template <int MODE>
__global__ void __launch_bounds__(256)
gemm_bt_kernel(const u16* __restrict__ A, const u16* __restrict__ Bt,
               const float* __restrict__ bias, float* __restrict__ Cout,
               u16* __restrict__ qws, u16* __restrict__ kws, u16* __restrict__ vtws,
               int Mdim, int Ndim, int Kdim) {
    __shared__ u16 As[2][128 * 32];
    __shared__ u16 Bs[2][128 * 32];

    const int tid  = threadIdx.x;
    const int w    = tid >> 6;
    const int lane = tid & 63;
    const int l15  = lane & 15;
    const int quad = lane >> 4;
    const int wm   = (w & 1) * 64;
    const int wn   = (w >> 1) * 64;
    const int m0   = blockIdx.y * 128;
    const int n0   = blockIdx.x * 128;

    const int row0  = tid >> 2;              // 0..63
    const int row1  = row0 + 64;             // 64..127
    const int col8  = (tid & 3) << 3;        // 0,8,16,24

    f32x4 acc[4][4];
#pragma unroll
    for (int i = 0; i < 4; ++i)
#pragma unroll
        for (int j = 0; j < 4; ++j) acc[i][j] = (f32x4){0.f, 0.f, 0.f, 0.f};

    auto stageA = [&](int buf, int kc) {
        if (MODE == 0) {
            int kcc = kc + col8, h = kcc >> 6, d = kcc & 63;
            int m = m0 + row0, b = m >> 11, t = m & 2047;
            GLL16(&A[(((size_t)(b * HH + h) * TT + t) * DH) + d], &As[buf][tid * 8]);
            m = m0 + row1; b = m >> 11; t = m & 2047;
            GLL16(&A[(((size_t)(b * HH + h) * TT + t) * DH) + d], &As[buf][(tid + 256) * 8]);
        } else {
            GLL16(&A[(size_t)(m0 + row0) * Kdim + kc + col8], &As[buf][tid * 8]);
            GLL16(&A[(size_t)(m0 + row1) * Kdim + kc + col8], &As[buf][(tid + 256) * 8]);
        }
    };

    // prologue: stage tile 0 into buffer 0
    stageA(0, 0);
    GLL16(&Bt[(size_t)(n0 + row0) * Kdim + col8], &Bs[0][tid * 8]);
    GLL16(&Bt[(size_t)(n0 + row1) * Kdim + col8], &Bs[0][(tid + 256) * 8]);

    const int nsteps = Kdim >> 5;
    for (int it = 0; it < nsteps; ++it) {
        const int buf = it & 1;
        __syncthreads();   // publishes tile `it` (drains its GLL16s — issued a full step ago)

        if (it + 1 < nsteps) {
            const int nbuf = buf ^ 1;
            const int kc = (it + 1) << 5;
            stageA(nbuf, kc);
            GLL16(&Bt[(size_t)(n0 + row0) * Kdim + kc + col8], &Bs[nbuf][tid * 8]);
            GLL16(&Bt[(size_t)(n0 + row1) * Kdim + kc + col8], &Bs[nbuf][(tid + 256) * 8]);
        }

        bf16x8 af[4], bfm[4];
#pragma unroll
        for (int mt = 0; mt < 4; ++mt)
            af[mt] = *(const bf16x8*)&As[buf][(wm + mt * 16 + l15) * 32 + quad * 8];
#pragma unroll
        for (int nt = 0; nt < 4; ++nt)
            bfm[nt] = *(const bf16x8*)&Bs[buf][(wn + nt * 16 + l15) * 32 + quad * 8];
#pragma unroll
        for (int mt = 0; mt < 4; ++mt)
#pragma unroll
            for (int nt = 0; nt < 4; ++nt)
                acc[mt][nt] = __builtin_amdgcn_mfma_f32_16x16x32_bf16(
                    af[mt], bfm[nt], acc[mt][nt], 0, 0, 0);
    }

    // epilogue: D row = quad*4+r, col = l15
#pragma unroll
    for (int mt = 0; mt < 4; ++mt) {
        int mrow_base = m0 + wm + mt * 16 + quad * 4;
#pragma unroll
        for (int nt = 0; nt < 4; ++nt) {
            int ncol = n0 + wn + nt * 16 + l15;
            float bv = bias[ncol];
            if (MODE == 0) {
#pragma unroll
                for (int r = 0; r < 4; ++r)
                    Cout[(size_t)(mrow_base + r) * Ndim + ncol] = acc[mt][nt][r] + bv;
            } else {
                int which = ncol >> 10, c = ncol & 1023;
                int h = c >> 6, d = c & 63;
                if (which == 2) {
                    // V^T: r spans 4 consecutive t -> packed store, with the
                    // key-permutation folded in: 4-key chunk [s3s2s1s0] -> [s3,s1,s0,s2]
                    int b = mrow_base >> 11, t = mrow_base & 2047;
                    int bh = b * HH + h;
                    int ch = (t >> 2) & 15;
                    int chp = (ch & 8) | (((ch >> 1) & 1) << 2) | ((ch & 1) << 1) | ((ch >> 2) & 1);
                    int tp = (t & ~63) | (chp << 2);
                    uint2 pv;
                    pv.x = cvt_pk_bf16(acc[mt][nt][0] + bv, acc[mt][nt][1] + bv);
                    pv.y = cvt_pk_bf16(acc[mt][nt][2] + bv, acc[mt][nt][3] + bv);
                    *(uint2*)&vtws[((size_t)bh * DH + d) * TT + tp] = pv;
                } else {
#pragma unroll
                    for (int r = 0; r < 4; ++r) {
                        int mrow = mrow_base + r;
                        int b = mrow >> 11, t = mrow & 2047;
                        int bh = b * HH + h;
                        float val = acc[mt][nt][r] + bv;
                        if (which == 0) {
                            // fold softmax scale and log2(e) into Q: 0.125*log2e
                            qws[((size_t)bh * TT + t) * DH + d] = f2bf(val * 0.18033688f);
                        } else {
                            kws[((size_t)bh * TT + t) * DH + d] = f2bf(val);
                        }
                    }
                }
            }
        }
    }
}

// ---------------- flash attention v11: zero-LDS P path, spill-fixed ----------------
// ROUND-15. r6 post-mortem: v10's algorithm is CORRECT (passed, absmax
// unchanged) but __launch_bounds__(256,4) capped unified VGPR+AGPR at 128
// while the datapath needs ~150 -> catastrophic scratch spill (WRITE_SIZE
// 16MB -> 420MB, attn 190us). ONE change: restore (256,3) (cap ~170, the
// bound r4 compiled cleanly under). Occupancy returns to ~3 blocks/CU =
// r4's level, isolating the zero-P-chain A/B vs r4's 78.1us.
// Chain per tile is now: barrier -> K/V b128 reads -> QK MFMA ->
// mask/exp2/cvt_pk -> PV MFMA. No P ds_writes, no lgkmcnt(0) drain, no
// P reads. LDS 34816B (Ps deleted).
__global__ void __launch_bounds__(256, 3)
attn_kernel(const u16* __restrict__ qws, const u16* __restrict__ kws,
            const u16* __restrict__ vtws, u16* __restrict__ yws) {
    __shared__ u16 Ks[2][64 * 68];   // K tile  [key][d], stride 68 u16 (bank-balanced)
    __shared__ u16 Vs[2][64 * 68];   // V^T tile [d][key-permuted]

    const int tid  = threadIdx.x;
    const int w    = tid >> 6;       // 0..3
    const int lane = tid & 63;
    const int l15  = lane & 15;
    const int quad = lane >> 4;
    const int bh   = blockIdx.x;     // fast index: co-locates same-bh blocks per XCD
    const int qt   = 15 - blockIdx.y;   // heavy tiles first

    const u16* Kbase = kws + (size_t)bh * TT * DH;
    const u16* Vbase = vtws + (size_t)bh * DH * TT;

    // staging: 256 threads x 32B each for K and V (fully coalesced)
    const int srow  = tid >> 2;          // 0..63
    const int sc16  = (tid & 3) << 4;    // 0,16,32,48 (u16 units)

    bf16x8 aones;
#pragma unroll
    for (int i = 0; i < 8; ++i) aones[i] = __builtin_bit_cast(bf16_t, (u16)0x3F80);

    const int q0     = qt * 128;
    const int qr0    = q0 + w * 32;    // this wave's 32 queries
    const int ntiles = (q0 + 128) >> 6;

    // Q fragments as B-operand (lane=query, contiguous d); scale+log2e folded
    const u16* Qp = qws + ((size_t)bh * TT + qr0) * DH;
    bf16x8 bqa[2], bqb[2];
#pragma unroll
    for (int kk = 0; kk < 2; ++kk) {
        bqa[kk] = *(const bf16x8*)&Qp[l15 * DH + kk * 32 + quad * 8];
        bqb[kk] = *(const bf16x8*)&Qp[(16 + l15) * DH + kk * 32 + quad * 8];
    }

    f32x4 o[2][4], ol[2];
#pragma unroll
    for (int qg = 0; qg < 2; ++qg) {
#pragma unroll
        for (int dt = 0; dt < 4; ++dt) o[qg][dt] = (f32x4){0.f, 0.f, 0.f, 0.f};
        ol[qg] = (f32x4){0.f, 0.f, 0.f, 0.f};
    }

    // prologue: tile 0 -> regs -> LDS[0]; tile 1 -> regs
    uint4 pk0 = *(const uint4*)&Kbase[(size_t)srow * DH + sc16];
    uint4 pk1 = *(const uint4*)&Kbase[(size_t)srow * DH + sc16 + 8];
    uint4 pv0 = *(const uint4*)&Vbase[(size_t)srow * TT + sc16];
    uint4 pv1 = *(const uint4*)&Vbase[(size_t)srow * TT + sc16 + 8];
    *(uint4*)&Ks[0][srow * 68 + sc16]     = pk0;
    *(uint4*)&Ks[0][srow * 68 + sc16 + 8] = pk1;
    *(uint4*)&Vs[0][srow * 68 + sc16]     = pv0;
    *(uint4*)&Vs[0][srow * 68 + sc16 + 8] = pv1;
    if (ntiles > 1) {
        pk0 = *(const uint4*)&Kbase[(size_t)(64 + srow) * DH + sc16];
        pk1 = *(const uint4*)&Kbase[(size_t)(64 + srow) * DH + sc16 + 8];
        pv0 = *(const uint4*)&Vbase[(size_t)srow * TT + 64 + sc16];
        pv1 = *(const uint4*)&Vbase[(size_t)srow * TT + 64 + sc16 + 8];
    }

    for (int it = 0; it < ntiles; ++it) {
        const int buf = it & 1;
        __syncthreads();   // publishes tile `it`; frees buffer buf^1

        if (it + 1 < ntiles) {
            *(uint4*)&Ks[buf ^ 1][srow * 68 + sc16]     = pk0;
            *(uint4*)&Ks[buf ^ 1][srow * 68 + sc16 + 8] = pk1;
            *(uint4*)&Vs[buf ^ 1][srow * 68 + sc16]     = pv0;
            *(uint4*)&Vs[buf ^ 1][srow * 68 + sc16 + 8] = pv1;
            if (it + 2 < ntiles) {
                int jn = (it + 2) << 6;
                pk0 = *(const uint4*)&Kbase[(size_t)(jn + srow) * DH + sc16];
                pk1 = *(const uint4*)&Kbase[(size_t)(jn + srow) * DH + sc16 + 8];
                pv0 = *(const uint4*)&Vbase[(size_t)srow * TT + jn + sc16];
                pv1 = *(const uint4*)&Vbase[(size_t)srow * TT + jn + sc16 + 8];
            }
        }

        const int j0 = it << 6;
        if (j0 > qr0 + 31) continue;   // fully masked for this wave (both q-groups)

        // ---- K fragments ONCE, reused by both q-groups ----
        bf16x8 ak[8];
#pragma unroll
        for (int kk = 0; kk < 2; ++kk)
#pragma unroll
            for (int kt = 0; kt < 4; ++kt)
                ak[kk * 4 + kt] =
                    *(const bf16x8*)&Ks[buf][(kt * 16 + l15) * 68 + kk * 32 + quad * 8];

        // ---- V fragments (natural b128 reads; permutation lives in vtws) ----
        bf16x8 avr[8];
#pragma unroll
        for (int kk = 0; kk < 2; ++kk)
#pragma unroll
            for (int dt = 0; dt < 4; ++dt)
                avr[kk * 4 + dt] =
                    *(const bf16x8*)&Vs[buf][(dt * 16 + l15) * 68 + kk * 32 + quad * 8];

        // ---- S^T = K @ Q^T for both q-groups ----
        f32x4 sa[4], sb[4];
#pragma unroll
        for (int kt = 0; kt < 4; ++kt) {
            sa[kt] = (f32x4){0.f, 0.f, 0.f, 0.f};
            sb[kt] = (f32x4){0.f, 0.f, 0.f, 0.f};
        }
#pragma unroll
        for (int kk = 0; kk < 2; ++kk)
#pragma unroll
            for (int kt = 0; kt < 4; ++kt)
                sa[kt] = __builtin_amdgcn_mfma_f32_16x16x32_bf16(ak[kk * 4 + kt], bqa[kk], sa[kt], 0, 0, 0);
#pragma unroll
        for (int kk = 0; kk < 2; ++kk)
#pragma unroll
            for (int kt = 0; kt < 4; ++kt)
                sb[kt] = __builtin_amdgcn_mfma_f32_16x16x32_bf16(ak[kk * 4 + kt], bqb[kk], sb[kt], 0, 0, 0);

        // causal mask (diagonal region only): key > query -> -inf
        if (j0 + 63 > qr0) {
            int qy0 = qr0 + l15;
            int qy1 = qr0 + 16 + l15;
#pragma unroll
            for (int kt = 0; kt < 4; ++kt)
#pragma unroll
                for (int r = 0; r < 4; ++r) {
                    int key = j0 + kt * 16 + quad * 4 + r;
                    if (key > qy0) sa[kt][r] = -INFINITY;
                    if (key > qy1) sb[kt][r] = -INFINITY;
                }
        }

        // ---- max-free softmax: p = exp2(s) ----
#pragma unroll
        for (int kt = 0; kt < 4; ++kt)
#pragma unroll
            for (int r = 0; r < 4; ++r) {
                sa[kt][r] = __builtin_amdgcn_exp2f(sa[kt][r]);
                sb[kt][r] = __builtin_amdgcn_exp2f(sb[kt][r]);
            }

        // ---- P -> PV B-operand DIRECTLY in-register: bp(kk) = pack(s[2kk],s[2kk+1]).
        // Slot->key bijection is matched by the permuted V^T layout. No LDS. ----
        uint4 ua0, ua1, ub0, ub1;
        ua0.x = cvt_pk_bf16(sa[0][0], sa[0][1]);
        ua0.y = cvt_pk_bf16(sa[0][2], sa[0][3]);
        ua0.z = cvt_pk_bf16(sa[1][0], sa[1][1]);
        ua0.w = cvt_pk_bf16(sa[1][2], sa[1][3]);
        ua1.x = cvt_pk_bf16(sa[2][0], sa[2][1]);
        ua1.y = cvt_pk_bf16(sa[2][2], sa[2][3]);
        ua1.z = cvt_pk_bf16(sa[3][0], sa[3][1]);
        ua1.w = cvt_pk_bf16(sa[3][2], sa[3][3]);
        ub0.x = cvt_pk_bf16(sb[0][0], sb[0][1]);
        ub0.y = cvt_pk_bf16(sb[0][2], sb[0][3]);
        ub0.z = cvt_pk_bf16(sb[1][0], sb[1][1]);
        ub0.w = cvt_pk_bf16(sb[1][2], sb[1][3]);
        ub1.x = cvt_pk_bf16(sb[2][0], sb[2][1]);
        ub1.y = cvt_pk_bf16(sb[2][2], sb[2][3]);
        ub1.z = cvt_pk_bf16(sb[3][0], sb[3][1]);
        ub1.w = cvt_pk_bf16(sb[3][2], sb[3][3]);
        bf16x8 bpa0 = __builtin_bit_cast(bf16x8, ua0);
        bf16x8 bpa1 = __builtin_bit_cast(bf16x8, ua1);
        bf16x8 bpb0 = __builtin_bit_cast(bf16x8, ub0);
        bf16x8 bpb1 = __builtin_bit_cast(bf16x8, ub1);

        // ---- O^T += V^T @ P^T ; l += ones @ P^T (fused row-sum) ----
#pragma unroll
        for (int dt = 0; dt < 4; ++dt)
            o[0][dt] = __builtin_amdgcn_mfma_f32_16x16x32_bf16(avr[dt], bpa0, o[0][dt], 0, 0, 0);
        ol[0] = __builtin_amdgcn_mfma_f32_16x16x32_bf16(aones, bpa0, ol[0], 0, 0, 0);
#pragma unroll
        for (int dt = 0; dt < 4; ++dt)
            o[0][dt] = __builtin_amdgcn_mfma_f32_16x16x32_bf16(avr[4 + dt], bpa1, o[0][dt], 0, 0, 0);
        ol[0] = __builtin_amdgcn_mfma_f32_16x16x32_bf16(aones, bpa1, ol[0], 0, 0, 0);
#pragma unroll
        for (int dt = 0; dt < 4; ++dt)
            o[1][dt] = __builtin_amdgcn_mfma_f32_16x16x32_bf16(avr[dt], bpb0, o[1][dt], 0, 0, 0);
        ol[1] = __builtin_amdgcn_mfma_f32_16x16x32_bf16(aones, bpb0, ol[1], 0, 0, 0);
#pragma unroll
        for (int dt = 0; dt < 4; ++dt)
            o[1][dt] = __builtin_amdgcn_mfma_f32_16x16x32_bf16(avr[4 + dt], bpb1, o[1][dt], 0, 0, 0);
        ol[1] = __builtin_amdgcn_mfma_f32_16x16x32_bf16(aones, bpb1, ol[1], 0, 0, 0);
    }

    // ---- normalize + store O^T to y[B,H,T,Dh] (coalesced) ----
#pragma unroll
    for (int qg = 0; qg < 2; ++qg) {
        float rinv = __builtin_amdgcn_rcpf(ol[qg][0]);   // l[query]; ~1ulp ok at bf16 out
        int t = qr0 + qg * 16 + l15;
#pragma unroll
        for (int dt = 0; dt < 4; ++dt) {
            uint2 yv;
            yv.x = cvt_pk_bf16(o[qg][dt][0] * rinv, o[qg][dt][1] * rinv);
            yv.y = cvt_pk_bf16(o[qg][dt][2] * rinv, o[qg][dt][3] * rinv);
            *(uint2*)&yws[((size_t)bh * TT + t) * DH + dt * 16 + quad * 4] = yv;
        }
    }
}

// ---------------- launch ----------------

extern "C" void kernel_launch(void* const* d_in, const int* in_sizes, int n_in,
                              void* d_out, int out_size, void* d_ws, size_t ws_size,
                              hipStream_t stream) {
    const float* x     = (const float*)d_in[0];
    const float* W_qkv = (const float*)d_in[1];
    const float* b_qkv = (const float*)d_in[2];
    const float* W_out = (const float*)d_in[3];
    const float* b_out = (const float*)d_in[4];
    float* out = (float*)d_out;

    char* ws = (char*)d_ws;
    u16* xb   = (u16*)ws; ws += (size_t)MM * CC * 2;       // x bf16        16 MB
    u16* wqt  = (u16*)ws; ws += (size_t)3 * CC * CC * 2;   // W_qkv^T bf16   6 MB
    u16* wot  = (u16*)ws; ws += (size_t)CC * CC * 2;       // W_out^T bf16   2 MB
    u16* qws  = (u16*)ws; ws += (size_t)MM * CC * 2;       // Q [B,H,T,Dh]  16 MB
    u16* kws  = (u16*)ws; ws += (size_t)MM * CC * 2;       // K [B,H,T,Dh]  16 MB
    u16* vtws = (u16*)ws; ws += (size_t)MM * CC * 2;       // V^T [B,H,Dh,T] (key-permuted) 16 MB
    u16* yws  = (u16*)ws; ws += (size_t)MM * CC * 2;       // y [B,H,T,Dh]  16 MB

    cast_x_kernel<<<(MM * CC / 4) / 256, 256, 0, stream>>>(x, xb, MM * CC / 4);
    transpose_cast_kernel<<<dim3(3 * CC / 32, CC / 32), 256, 0, stream>>>(W_qkv, wqt, CC, 3 * CC);
    transpose_cast_kernel<<<dim3(CC / 32, CC / 32), 256, 0, stream>>>(W_out, wot, CC, CC);

    gemm_bt_kernel<1><<<dim3(24, 64), 256, 0, stream>>>(
        xb, wqt, b_qkv, nullptr, qws, kws, vtws, MM, 3 * CC, CC);

    attn_kernel<<<dim3(BB * HH, 16), 256, 0, stream>>>(qws, kws, vtws, yws);

    gemm_bt_kernel<0><<<dim3(8, 64), 256, 0, stream>>>(
        yws, wot, b_out, out, nullptr, nullptr, nullptr, MM, CC, CC);
}